// Round 1
// baseline (76.563 us; speedup 1.0000x reference)
//
#include <hip/hip_runtime.h>

#define BB 32
#define CC 384
#define TT 512
#define MAXF 6656      // T * 13
#define CG 8           // channels per block
#define NCHUNK 7       // ceil(6656 / 1024), last chunk is half

// Workspace layout: [0,128) fl ints (32 used), [128, 128+BB*MAXF*2) tok ushorts
#define WS_NEEDED (128 + (size_t)BB * MAXF * 2)

__device__ __forceinline__ int rep_count(float d) {
    float fr = 44100.0f * d;
    float rf;
    if (fr - 1024.0f > 0.0f) rf = fmaxf((fr - 1024.0f) * (1.0f / 256.0f), 1.0f);
    else rf = (d == 0.0f) ? 0.0f : 1.0f;
    return (int)rf;
}

// ---------------------------------------------------------------------------
// Kernel A: per-batch scan + token scatter into workspace. 32 blocks.
// ---------------------------------------------------------------------------
__global__ __launch_bounds__(256) void lr_scan_kernel(
        const float* __restrict__ duration,
        unsigned short* __restrict__ tok_ws,
        int* __restrict__ fl_ws,
        float* __restrict__ fl_out) {
    __shared__ unsigned short stok[MAXF];   // 13 KB
    __shared__ int wsum[4];

    const int b    = blockIdx.x;
    const int tid  = threadIdx.x;
    const int lane = tid & 63;
    const int wid  = tid >> 6;

    const float2 dp = *(const float2*)(duration + b * TT + 2 * tid);
    const int r0 = rep_count(dp.x);
    const int r1 = rep_count(dp.y);
    const int s  = r0 + r1;

    // wave-level inclusive scan of pair sums (no barriers)
    int v = s;
    #pragma unroll
    for (int off = 1; off < 64; off <<= 1) {
        int t = __shfl_up(v, off, 64);
        if (lane >= off) v += t;
    }
    if (lane == 63) wsum[wid] = v;

    // zero-fill stok while the scan combine waits (tok beyond fl must be 0)
    {
        unsigned int* sz = (unsigned int*)stok;
        #pragma unroll
        for (int i = tid; i < MAXF / 2; i += 256) sz[i] = 0;
    }
    __syncthreads();

    int prefix = 0, total = 0;
    #pragma unroll
    for (int w = 0; w < 4; ++w) {
        const int t = wsum[w];
        total += t;
        if (w < wid) prefix += t;
    }
    const int incl = v + prefix;     // cum over pairs -> cum[2*tid+1]
    const int excl = incl - s;       // start frame of token 2*tid
    const int fl   = total;

    // scatter: token t owns frames [excl_t, excl_t + r_t)
    for (int f = excl; f < excl + r0; ++f) stok[f] = (unsigned short)(2 * tid);
    for (int f = excl + r0; f < incl; ++f) stok[f] = (unsigned short)(2 * tid + 1);
    __syncthreads();

    // coalesced copy LDS -> workspace (MAXF/8 = 832 uint4)
    {
        const uint4* src = (const uint4*)stok;
        uint4* dst = (uint4*)(tok_ws + (size_t)b * MAXF);
        #pragma unroll
        for (int i = tid; i < MAXF / 8; i += 256) dst[i] = src[i];
    }
    if (tid == 0) {
        fl_ws[b]  = fl;
        fl_out[b] = (float)fl;
    }
}

// ---------------------------------------------------------------------------
// Kernel B: pure streaming gather/store. 18 KB LDS, 1 barrier, target 8 blk/CU.
// ---------------------------------------------------------------------------
__global__ __launch_bounds__(256, 8) void lr_write_kernel(
        const float* __restrict__ x,
        const float* __restrict__ notepitch,
        const unsigned short* __restrict__ tok_ws,
        const int* __restrict__ fl_ws,
        float* __restrict__ out,
        float* __restrict__ pitch_out) {
    __shared__ float xs[CG * TT];    // 16 KB
    __shared__ float snp[TT];        // 2 KB

    const int b   = blockIdx.y;
    const int cg  = blockIdx.x;
    const int tid = threadIdx.x;
    const bool do_pitch = (cg == 0);

    const int fl = fl_ws[b];         // uniform -> s_load

    // stage x rows (and pitch row for cg==0) into LDS
    {
        const float4* xsrc = (const float4*)(x + ((size_t)(b * CC + cg * CG)) * TT);
        float4* xdst = (float4*)xs;
        const float4 a0 = xsrc[tid];
        const float4 a1 = xsrc[256 + tid];
        const float4 a2 = xsrc[512 + tid];
        const float4 a3 = xsrc[768 + tid];
        xdst[tid] = a0; xdst[256 + tid] = a1;
        xdst[512 + tid] = a2; xdst[768 + tid] = a3;
        if (do_pitch)
            *(float2*)(snp + 2 * tid) = *(const float2*)(notepitch + b * TT + 2 * tid);
    }
    __syncthreads();

    float* const obase = out + ((size_t)(b * CC + cg * CG)) * MAXF;
    const unsigned short* tokb = tok_ws + (size_t)b * MAXF;
    const float4 z = make_float4(0.f, 0.f, 0.f, 0.f);

    #pragma unroll
    for (int ch = 0; ch < NCHUNK; ++ch) {
        const int base = ch * 1024;
        const int p0 = base + tid * 4;
        if (p0 >= MAXF) continue;               // only trims chunk 6 tail

        if (base >= fl) {
            // pure zero chunk
            #pragma unroll
            for (int c = 0; c < CG; ++c)
                *(float4*)(obase + (size_t)c * MAXF + p0) = z;
            if (do_pitch)
                *(float4*)(pitch_out + (size_t)b * MAXF + p0) = z;
        } else if (base + 1024 <= fl) {
            // fully valid chunk: unmasked gathers
            const ushort4 tk = *(const ushort4*)(tokb + p0);
            const int u0 = tk.x, u1 = tk.y, u2 = tk.z, u3 = tk.w;
            #pragma unroll
            for (int c = 0; c < CG; ++c) {
                const float* xr = xs + c * TT;
                *(float4*)(obase + (size_t)c * MAXF + p0) =
                    make_float4(xr[u0], xr[u1], xr[u2], xr[u3]);
            }
            if (do_pitch)
                *(float4*)(pitch_out + (size_t)b * MAXF + p0) =
                    make_float4((float)(int)snp[u0], (float)(int)snp[u1],
                                (float)(int)snp[u2], (float)(int)snp[u3]);
        } else {
            // mixed chunk: tok beyond fl is 0 (pre-zeroed in kernel A) -> no clamp
            const ushort4 tk = *(const ushort4*)(tokb + p0);
            const int u0 = tk.x, u1 = tk.y, u2 = tk.z, u3 = tk.w;
            const bool m0 = p0 < fl, m1 = p0 + 1 < fl;
            const bool m2 = p0 + 2 < fl, m3 = p0 + 3 < fl;
            #pragma unroll
            for (int c = 0; c < CG; ++c) {
                const float* xr = xs + c * TT;
                float4 v;
                v.x = m0 ? xr[u0] : 0.f;
                v.y = m1 ? xr[u1] : 0.f;
                v.z = m2 ? xr[u2] : 0.f;
                v.w = m3 ? xr[u3] : 0.f;
                *(float4*)(obase + (size_t)c * MAXF + p0) = v;
            }
            if (do_pitch) {
                float4 pv;
                pv.x = m0 ? (float)(int)snp[u0] : 0.f;
                pv.y = m1 ? (float)(int)snp[u1] : 0.f;
                pv.z = m2 ? (float)(int)snp[u2] : 0.f;
                pv.w = m3 ? (float)(int)snp[u3] : 0.f;
                *(float4*)(pitch_out + (size_t)b * MAXF + p0) = pv;
            }
        }
    }
}

// ---------------------------------------------------------------------------
// Fallback: previous fused single-kernel version (used if workspace too small)
// ---------------------------------------------------------------------------
__global__ __launch_bounds__(256) void lr_fused_kernel(
        const float* __restrict__ x,
        const float* __restrict__ notepitch,
        const float* __restrict__ duration,
        float* __restrict__ out,
        float* __restrict__ pitch_out,
        float* __restrict__ fl_out) {
    __shared__ float xs[CG * TT];
    __shared__ float snp[TT];
    __shared__ int   sbuf[256];
    __shared__ __attribute__((aligned(16))) unsigned short stok[MAXF];

    const int b   = blockIdx.y;
    const int cg  = blockIdx.x;
    const int tid = threadIdx.x;
    const bool do_pitch = (cg == 0);

    const float4* xsrc = (const float4*)(x + ((size_t)(b * CC + cg * CG)) * TT);
    const float4 xa0 = xsrc[tid];
    const float4 xa1 = xsrc[256 + tid];
    const float4 xa2 = xsrc[512 + tid];
    const float4 xa3 = xsrc[768 + tid];
    float2 np2 = make_float2(0.f, 0.f);
    if (do_pitch) np2 = *(const float2*)(notepitch + b * TT + 2 * tid);

    const float2 dp = *(const float2*)(duration + b * TT + 2 * tid);
    const int r0 = rep_count(dp.x);
    const int r1 = rep_count(dp.y);
    const int s = r0 + r1;

    sbuf[tid] = s;
    __syncthreads();
    for (int off = 1; off < 256; off <<= 1) {
        const int add = (tid >= off) ? sbuf[tid - off] : 0;
        __syncthreads();
        sbuf[tid] += add;
        __syncthreads();
    }
    const int incl = sbuf[tid];
    const int excl = incl - s;
    const int fl   = sbuf[255];

    if (do_pitch && tid == 0) fl_out[b] = (float)fl;

    {
        float4* xdst = (float4*)xs;
        xdst[tid] = xa0; xdst[256 + tid] = xa1;
        xdst[512 + tid] = xa2; xdst[768 + tid] = xa3;
    }
    if (do_pitch) *(float2*)(snp + 2 * tid) = np2;

    float* const obase = out + ((size_t)(b * CC + cg * CG)) * MAXF;
    const float4 z = make_float4(0.f, 0.f, 0.f, 0.f);

    #pragma unroll
    for (int ch = 0; ch < NCHUNK; ++ch) {
        const int base = ch * 1024;
        const int p0 = base + tid * 4;
        if (base >= fl && p0 < MAXF) {
            #pragma unroll
            for (int c = 0; c < CG; ++c)
                *(float4*)(obase + (size_t)c * MAXF + p0) = z;
            if (do_pitch)
                *(float4*)(pitch_out + (size_t)b * MAXF + p0) = z;
        }
    }

    for (int f = excl; f < excl + r0; ++f)       stok[f] = (unsigned short)(2 * tid);
    for (int f = excl + r0; f < incl; ++f)       stok[f] = (unsigned short)(2 * tid + 1);
    __syncthreads();

    for (int ch = 0; ch < NCHUNK; ++ch) {
        const int base = ch * 1024;
        const int p0 = base + tid * 4;
        if (base >= fl || p0 >= MAXF) continue;

        if (base + 1024 <= fl) {
            const ushort4 tk = *(const ushort4*)(stok + p0);
            const int u0 = tk.x, u1 = tk.y, u2 = tk.z, u3 = tk.w;
            #pragma unroll
            for (int c = 0; c < CG; ++c) {
                const float* xr = xs + c * TT;
                *(float4*)(obase + (size_t)c * MAXF + p0) =
                    make_float4(xr[u0], xr[u1], xr[u2], xr[u3]);
            }
            if (do_pitch)
                *(float4*)(pitch_out + (size_t)b * MAXF + p0) =
                    make_float4((float)(int)snp[u0], (float)(int)snp[u1],
                                (float)(int)snp[u2], (float)(int)snp[u3]);
        } else {
            const ushort4 tk = *(const ushort4*)(stok + p0);
            const int u0 = min((int)tk.x, TT - 1), u1 = min((int)tk.y, TT - 1);
            const int u2 = min((int)tk.z, TT - 1), u3 = min((int)tk.w, TT - 1);
            const bool m0 = p0 < fl, m1 = p0 + 1 < fl;
            const bool m2 = p0 + 2 < fl, m3 = p0 + 3 < fl;
            #pragma unroll
            for (int c = 0; c < CG; ++c) {
                const float* xr = xs + c * TT;
                float4 v;
                v.x = m0 ? xr[u0] : 0.f;
                v.y = m1 ? xr[u1] : 0.f;
                v.z = m2 ? xr[u2] : 0.f;
                v.w = m3 ? xr[u3] : 0.f;
                *(float4*)(obase + (size_t)c * MAXF + p0) = v;
            }
            if (do_pitch) {
                float4 pv;
                pv.x = m0 ? (float)(int)snp[u0] : 0.f;
                pv.y = m1 ? (float)(int)snp[u1] : 0.f;
                pv.z = m2 ? (float)(int)snp[u2] : 0.f;
                pv.w = m3 ? (float)(int)snp[u3] : 0.f;
                *(float4*)(pitch_out + (size_t)b * MAXF + p0) = pv;
            }
        }
    }
}

extern "C" void kernel_launch(void* const* d_in, const int* in_sizes, int n_in,
                              void* d_out, int out_size, void* d_ws, size_t ws_size,
                              hipStream_t stream) {
    (void)in_sizes; (void)n_in; (void)out_size;

    const float* x         = (const float*)d_in[0];  // (B, C, T)
    const float* notepitch = (const float*)d_in[1];  // (B, T)
    const float* duration  = (const float*)d_in[2];  // (B, T)
    // d_in[3] = x_lengths — unused by the reference computation

    float* out       = (float*)d_out;                    // (B, C, MAXF)
    float* pitch_out = out + (size_t)BB * CC * MAXF;     // (B, MAXF)
    float* fl_out    = pitch_out + (size_t)BB * MAXF;    // (B,)

    if (d_ws != nullptr && ws_size >= WS_NEEDED) {
        int* fl_ws = (int*)d_ws;
        unsigned short* tok_ws = (unsigned short*)((char*)d_ws + 128);

        lr_scan_kernel<<<BB, 256, 0, stream>>>(duration, tok_ws, fl_ws, fl_out);

        dim3 g(CC / CG, BB);   // 48 x 32 = 1536 blocks
        lr_write_kernel<<<g, 256, 0, stream>>>(x, notepitch, tok_ws, fl_ws,
                                               out, pitch_out);
    } else {
        dim3 g(CC / CG, BB);
        lr_fused_kernel<<<g, 256, 0, stream>>>(x, notepitch, duration,
                                               out, pitch_out, fl_out);
    }
}

// Round 2
// 72.704 us; speedup vs baseline: 1.0531x; 1.0531x over previous
//
#include <hip/hip_runtime.h>

#define BB 32
#define CC 384
#define TT 512
#define MAXF 6656      // T * 13
#define CG 8           // channels per block (2 per wave)
#define NIT 26         // MAXF / 256 frames per wave-iteration (exact)

__device__ __forceinline__ int rep_count(float d) {
    float fr = 44100.0f * d;
    float rf;
    if (fr - 1024.0f > 0.0f) rf = fmaxf((fr - 1024.0f) * (1.0f / 256.0f), 1.0f);
    else rf = (d == 0.0f) ? 0.0f : 1.0f;
    return (int)rf;
}

// Barrier-free fused kernel. grid = (CC/CG, BB), 256 threads = 4 waves.
// Each wave is fully independent: it scans all 512 tokens redundantly
// (shuffle scan, no LDS), scatters the FULL stok array redundantly
// (benign race: identical values), and stages/gathers only its own 2
// channel rows. Zero __syncthreads => no vmcnt(0) drains, no phase sync.
__global__ __launch_bounds__(256) void lr_nobar_kernel(
        const float* __restrict__ x,
        const float* __restrict__ notepitch,
        const float* __restrict__ duration,
        float* __restrict__ out,
        float* __restrict__ pitch_out,
        float* __restrict__ fl_out) {
    __shared__ float xs[CG * TT];                                    // 16 KB
    __shared__ float snp[TT];                                        // 2 KB
    __shared__ __attribute__((aligned(16))) unsigned short stok[MAXF]; // 13 KB

    const int b    = blockIdx.y;
    const int cg   = blockIdx.x;
    const int tid  = threadIdx.x;
    const int lane = tid & 63;
    const int wid  = tid >> 6;
    const bool pw  = (cg == 0) && (wid == 0);   // pitch-owning wave

    // ---- duration load FIRST: the scan's waitcnt then leaves x-loads in flight
    const float4* dsrc = (const float4*)(duration + b * TT);
    const float4 d0 = dsrc[2 * lane];
    const float4 d1 = dsrc[2 * lane + 1];

    // ---- issue this wave's 2 x-rows (latency overlapped with scan + zeros)
    const int row0 = 2 * wid;
    const float4* xsrc = (const float4*)(x + ((size_t)(b * CC + cg * CG + row0)) * TT);
    const float4 a0 = xsrc[2 * lane];
    const float4 a1 = xsrc[2 * lane + 1];
    const float4 a2 = xsrc[128 + 2 * lane];
    const float4 a3 = xsrc[128 + 2 * lane + 1];
    float4 np0 = make_float4(0.f, 0.f, 0.f, 0.f), np1 = np0;
    if (pw) {
        const float4* npsrc = (const float4*)(notepitch + b * TT);
        np0 = npsrc[2 * lane];
        np1 = npsrc[2 * lane + 1];
    }

    // ---- redundant per-wave scan over all 512 tokens (8 per lane) ----
    int r[8];
    r[0] = rep_count(d0.x); r[1] = rep_count(d0.y);
    r[2] = rep_count(d0.z); r[3] = rep_count(d0.w);
    r[4] = rep_count(d1.x); r[5] = rep_count(d1.y);
    r[6] = rep_count(d1.z); r[7] = rep_count(d1.w);
    const int local = r[0]+r[1]+r[2]+r[3]+r[4]+r[5]+r[6]+r[7];

    int v = local;
    #pragma unroll
    for (int off = 1; off < 64; off <<= 1) {
        const int t = __shfl_up(v, off, 64);
        if (lane >= off) v += t;
    }
    const int fl = __shfl(v, 63, 64);           // frame_lengths[b]

    if (pw && lane == 0) fl_out[b] = (float)fl;

    // ---- zero stores ASAP: need only fl, not x and not stok ----
    float* const ob0 = out + ((size_t)(b * CC + cg * CG + row0)) * MAXF;
    float* const ob1 = ob0 + MAXF;
    float* const pb  = pitch_out + (size_t)b * MAXF;
    const float4 z = make_float4(0.f, 0.f, 0.f, 0.f);

    #pragma unroll
    for (int it = 0; it < NIT; ++it) {
        const int base = it * 256;
        if (base >= fl) {
            const int p0 = base + lane * 4;
            *(float4*)(ob0 + p0) = z;
            *(float4*)(ob1 + p0) = z;
            if (pw) *(float4*)(pb + p0) = z;
        }
    }

    // ---- stage this wave's 2 rows into LDS (loads have arrived by now) ----
    float* const xr0 = xs + row0 * TT;
    float* const xr1 = xr0 + TT;
    ((float4*)xr0)[2 * lane]       = a0;
    ((float4*)xr0)[2 * lane + 1]   = a1;
    ((float4*)xr1)[2 * lane]       = a2;
    ((float4*)xr1)[2 * lane + 1]   = a3;
    if (pw) {
        ((float4*)snp)[2 * lane]     = np0;
        ((float4*)snp)[2 * lane + 1] = np1;
    }

    // ---- redundant scatter: each wave writes the FULL stok for [0, fl) ----
    // (identical values across waves -> benign race; own-wave program order
    //  guarantees this wave's gather reads are covered)
    {
        int f = v - local;                      // exclusive prefix at token 8*lane
        #pragma unroll
        for (int k = 0; k < 8; ++k) {
            const unsigned short tv = (unsigned short)(8 * lane + k);
            const int fe = f + r[k];
            for (; f < fe; ++f) stok[f] = tv;
        }
    }

    // ---- gather + store valid/mixed iterations ----
    for (int it = 0; it < NIT; ++it) {
        const int base = it * 256;
        if (base >= fl) continue;
        const int p0 = base + lane * 4;
        const ushort4 tk = *(const ushort4*)(stok + p0);

        if (base + 256 <= fl) {
            // fully valid: unmasked gathers (tok < 512 guaranteed)
            const int u0 = tk.x, u1 = tk.y, u2 = tk.z, u3 = tk.w;
            *(float4*)(ob0 + p0) = make_float4(xr0[u0], xr0[u1], xr0[u2], xr0[u3]);
            *(float4*)(ob1 + p0) = make_float4(xr1[u0], xr1[u1], xr1[u2], xr1[u3]);
            if (pw)
                *(float4*)(pb + p0) =
                    make_float4((float)(int)snp[u0], (float)(int)snp[u1],
                                (float)(int)snp[u2], (float)(int)snp[u3]);
        } else {
            // mixed: stok beyond fl is uninitialized -> clamp + mask
            const int u0 = min((int)tk.x, TT - 1), u1 = min((int)tk.y, TT - 1);
            const int u2 = min((int)tk.z, TT - 1), u3 = min((int)tk.w, TT - 1);
            const bool m0 = p0 < fl, m1 = p0 + 1 < fl;
            const bool m2 = p0 + 2 < fl, m3 = p0 + 3 < fl;
            float4 v0, v1;
            v0.x = m0 ? xr0[u0] : 0.f;  v0.y = m1 ? xr0[u1] : 0.f;
            v0.z = m2 ? xr0[u2] : 0.f;  v0.w = m3 ? xr0[u3] : 0.f;
            v1.x = m0 ? xr1[u0] : 0.f;  v1.y = m1 ? xr1[u1] : 0.f;
            v1.z = m2 ? xr1[u2] : 0.f;  v1.w = m3 ? xr1[u3] : 0.f;
            *(float4*)(ob0 + p0) = v0;
            *(float4*)(ob1 + p0) = v1;
            if (pw) {
                float4 pv;
                pv.x = m0 ? (float)(int)snp[u0] : 0.f;
                pv.y = m1 ? (float)(int)snp[u1] : 0.f;
                pv.z = m2 ? (float)(int)snp[u2] : 0.f;
                pv.w = m3 ? (float)(int)snp[u3] : 0.f;
                *(float4*)(pb + p0) = pv;
            }
        }
    }
}

extern "C" void kernel_launch(void* const* d_in, const int* in_sizes, int n_in,
                              void* d_out, int out_size, void* d_ws, size_t ws_size,
                              hipStream_t stream) {
    (void)in_sizes; (void)n_in; (void)out_size; (void)d_ws; (void)ws_size;

    const float* x         = (const float*)d_in[0];  // (B, C, T)
    const float* notepitch = (const float*)d_in[1];  // (B, T)
    const float* duration  = (const float*)d_in[2];  // (B, T)
    // d_in[3] = x_lengths — unused by the reference computation

    float* out       = (float*)d_out;                    // (B, C, MAXF)
    float* pitch_out = out + (size_t)BB * CC * MAXF;     // (B, MAXF)
    float* fl_out    = pitch_out + (size_t)BB * MAXF;    // (B,)

    dim3 g(CC / CG, BB);   // 48 x 32 = 1536 blocks, 4 waves each
    lr_nobar_kernel<<<g, 256, 0, stream>>>(x, notepitch, duration,
                                           out, pitch_out, fl_out);
}

// Round 3
// 69.114 us; speedup vs baseline: 1.1078x; 1.0520x over previous
//
#include <hip/hip_runtime.h>

#define BB 32
#define CC 384
#define TT 512
#define MAXF 6656      // T * 13
#define CG 8           // channels per block
#define NCHUNK 7       // ceil(6656 / 1024), last chunk is half

typedef float f32x4 __attribute__((ext_vector_type(4)));

__device__ __forceinline__ void nt_store4(float* p, float a, float b, float c, float d) {
    f32x4 v; v.x = a; v.y = b; v.z = c; v.w = d;
    __builtin_nontemporal_store(v, (f32x4*)p);
}

__device__ __forceinline__ void nt_zero4(float* p) {
    f32x4 v = (f32x4)0.0f;
    __builtin_nontemporal_store(v, (f32x4*)p);
}

__device__ __forceinline__ int rep_count(float d) {
    float fr = 44100.0f * d;
    float rf;
    if (fr - 1024.0f > 0.0f) rf = fmaxf((fr - 1024.0f) * (1.0f / 256.0f), 1.0f);
    else rf = (d == 0.0f) ? 0.0f : 1.0f;
    return (int)rf;
}

// Round-0 skeleton (best measured: 69.1us) + shuffle scan (17 barriers -> 2)
// + nontemporal output stores (L2-bypass for the 328 MB write stream).
__global__ __launch_bounds__(256) void lr_fused_nt_kernel(
        const float* __restrict__ x,
        const float* __restrict__ notepitch,
        const float* __restrict__ duration,
        float* __restrict__ out,
        float* __restrict__ pitch_out,
        float* __restrict__ fl_out) {
    __shared__ float xs[CG * TT];                                      // 16 KB
    __shared__ float snp[TT];                                          // 2 KB
    __shared__ __attribute__((aligned(16))) unsigned short stok[MAXF]; // 13 KB
    __shared__ int wsum[4];

    const int b    = blockIdx.y;
    const int cg   = blockIdx.x;
    const int tid  = threadIdx.x;
    const int lane = tid & 63;
    const int wid  = tid >> 6;
    const bool do_pitch = (cg == 0);

    // ---- duration first (scan's waitcnt then leaves x loads in flight) ----
    const float2 dp = *(const float2*)(duration + b * TT + 2 * tid);

    // ---- issue x staging loads (latency overlapped with scan + zero phase) ----
    const float4* xsrc = (const float4*)(x + ((size_t)(b * CC + cg * CG)) * TT);
    const float4 xa0 = xsrc[tid];
    const float4 xa1 = xsrc[256 + tid];
    const float4 xa2 = xsrc[512 + tid];
    const float4 xa3 = xsrc[768 + tid];
    float2 np2 = make_float2(0.f, 0.f);
    if (do_pitch) np2 = *(const float2*)(notepitch + b * TT + 2 * tid);

    // ---- repeat counts for tokens 2*tid, 2*tid+1 ----
    const int r0 = rep_count(dp.x);
    const int r1 = rep_count(dp.y);
    const int s  = r0 + r1;

    // ---- shuffle scan of pair sums within wave, LDS combine across waves ----
    int v = s;
    #pragma unroll
    for (int off = 1; off < 64; off <<= 1) {
        const int t = __shfl_up(v, off, 64);
        if (lane >= off) v += t;
    }
    if (lane == 63) wsum[wid] = v;
    __syncthreads();

    int prefix = 0, total = 0;
    #pragma unroll
    for (int w = 0; w < 4; ++w) {
        const int t = wsum[w];
        total += t;
        if (w < wid) prefix += t;
    }
    const int incl = v + prefix;     // inclusive over pairs -> cum[2*tid+1]
    const int excl = incl - s;       // start frame of token 2*tid
    const int fl   = total;          // frame_lengths[b]

    if (do_pitch && tid == 0) fl_out[b] = (float)fl;

    float* const obase = out + ((size_t)(b * CC + cg * CG)) * MAXF;
    float* const pb    = pitch_out + (size_t)b * MAXF;

    // ---- phase 1: pure zero chunks (need only fl, not stok, not x) ----
    #pragma unroll
    for (int ch = 0; ch < NCHUNK; ++ch) {
        const int base = ch * 1024;
        const int p0 = base + tid * 4;
        if (base >= fl && p0 < MAXF) {
            #pragma unroll
            for (int c = 0; c < CG; ++c)
                nt_zero4(obase + (size_t)c * MAXF + p0);
            if (do_pitch)
                nt_zero4(pb + p0);
        }
    }

    // ---- stage x rows / pitch into LDS (loads have arrived by now) ----
    {
        float4* xdst = (float4*)xs;
        xdst[tid] = xa0; xdst[256 + tid] = xa1;
        xdst[512 + tid] = xa2; xdst[768 + tid] = xa3;
    }
    if (do_pitch) *(float2*)(snp + 2 * tid) = np2;

    // ---- scatter inversion: token t owns frames [excl_t, excl_t + r_t) ----
    for (int f = excl; f < excl + r0; ++f)       stok[f] = (unsigned short)(2 * tid);
    for (int f = excl + r0; f < incl; ++f)       stok[f] = (unsigned short)(2 * tid + 1);
    __syncthreads();

    // ---- phase 2: valid / mixed chunks ----
    for (int ch = 0; ch < NCHUNK; ++ch) {
        const int base = ch * 1024;
        const int p0 = base + tid * 4;
        if (base >= fl || p0 >= MAXF) continue;

        if (base + 1024 <= fl) {
            // fully valid: unmasked gathers
            const ushort4 tk = *(const ushort4*)(stok + p0);
            const int u0 = tk.x, u1 = tk.y, u2 = tk.z, u3 = tk.w;
            #pragma unroll
            for (int c = 0; c < CG; ++c) {
                const float* xr = xs + c * TT;
                nt_store4(obase + (size_t)c * MAXF + p0,
                          xr[u0], xr[u1], xr[u2], xr[u3]);
            }
            if (do_pitch)
                nt_store4(pb + p0,
                          (float)(int)snp[u0], (float)(int)snp[u1],
                          (float)(int)snp[u2], (float)(int)snp[u3]);
        } else {
            // mixed: clamp garbage tokens (stok uninit beyond fl), mask tail
            const ushort4 tk = *(const ushort4*)(stok + p0);
            const int u0 = min((int)tk.x, TT - 1), u1 = min((int)tk.y, TT - 1);
            const int u2 = min((int)tk.z, TT - 1), u3 = min((int)tk.w, TT - 1);
            const bool m0 = p0 < fl, m1 = p0 + 1 < fl;
            const bool m2 = p0 + 2 < fl, m3 = p0 + 3 < fl;
            #pragma unroll
            for (int c = 0; c < CG; ++c) {
                const float* xr = xs + c * TT;
                nt_store4(obase + (size_t)c * MAXF + p0,
                          m0 ? xr[u0] : 0.f,
                          m1 ? xr[u1] : 0.f,
                          m2 ? xr[u2] : 0.f,
                          m3 ? xr[u3] : 0.f);
            }
            if (do_pitch) {
                nt_store4(pb + p0,
                          m0 ? (float)(int)snp[u0] : 0.f,
                          m1 ? (float)(int)snp[u1] : 0.f,
                          m2 ? (float)(int)snp[u2] : 0.f,
                          m3 ? (float)(int)snp[u3] : 0.f);
            }
        }
    }
}

extern "C" void kernel_launch(void* const* d_in, const int* in_sizes, int n_in,
                              void* d_out, int out_size, void* d_ws, size_t ws_size,
                              hipStream_t stream) {
    (void)in_sizes; (void)n_in; (void)out_size; (void)d_ws; (void)ws_size;

    const float* x         = (const float*)d_in[0];  // (B, C, T)
    const float* notepitch = (const float*)d_in[1];  // (B, T)
    const float* duration  = (const float*)d_in[2];  // (B, T)
    // d_in[3] = x_lengths — unused by the reference computation

    float* out       = (float*)d_out;                    // (B, C, MAXF)
    float* pitch_out = out + (size_t)BB * CC * MAXF;     // (B, MAXF)
    float* fl_out    = pitch_out + (size_t)BB * MAXF;    // (B,)

    dim3 g(CC / CG, BB);   // 48 x 32 = 1536 blocks
    lr_fused_nt_kernel<<<g, 256, 0, stream>>>(x, notepitch, duration,
                                              out, pitch_out, fl_out);
}